// Round 1
// baseline (529.822 us; speedup 1.0000x reference)
//
#include <hip/hip_runtime.h>

// VQ-VAE quantization, fp32 correctness-first baseline.
// N=32768 latent vectors (D=256), K=1024 codes.
// dist = ||e_k||^2 - 2 z.e_k  (||z||^2 dropped: constant per row, argmin-invariant)

#define N_ROWS 32768
#define K_CODES 1024
#define D_DIM 256
#define M_ELEMS 8388608   // N_ROWS * D_DIM

#define TM 128            // rows per block
#define TN 128            // codes per block
#define TK 32             // D chunk
#define LDSS 36           // LDS row stride (floats): conflict-free for our read pattern, keeps 16B align

// ---------------- codebook norms ----------------
__global__ void norms_kernel(const float* __restrict__ cbk, float* __restrict__ norms) {
    int wave = threadIdx.x >> 6;            // 4 waves/block, one code each
    int lane = threadIdx.x & 63;
    int code = blockIdx.x * 4 + wave;       // grid = K/4 = 256
    const float4 v = *(const float4*)(cbk + (size_t)code * D_DIM + lane * 4);
    float s = v.x * v.x + v.y * v.y + v.z * v.z + v.w * v.w;
    #pragma unroll
    for (int off = 32; off; off >>= 1) s += __shfl_down(s, off);
    if (lane == 0) norms[code] = s;
}

// ---------------- main distance + partial argmin ----------------
__global__ __launch_bounds__(256, 2) void vq_main_kernel(
    const float* __restrict__ z, const float* __restrict__ cbk,
    const float* __restrict__ norms,
    float* __restrict__ pval, int* __restrict__ pidx) {
    __shared__ __align__(16) float As[TM * LDSS];
    __shared__ __align__(16) float Bs[TN * LDSS];

    const int tid = threadIdx.x;
    const int tx = tid & 15;        // code dim (x8 strided 16 -> 128 codes)
    const int ty = tid >> 4;        // row dim  (x8 strided 16 -> 128 rows)
    const int bid = blockIdx.x;     // grid = (N/TM) * (K/TN) = 256*8 = 2048
    const int cbl = bid & 7;
    const int rb  = bid >> 3;
    const int rbase = rb * TM;
    const int cbase = cbl * TN;

    float acc[8][8];
    #pragma unroll
    for (int i = 0; i < 8; ++i)
        #pragma unroll
        for (int j = 0; j < 8; ++j) acc[i][j] = 0.f;

    for (int dc = 0; dc < D_DIM / TK; ++dc) {
        // stage A (rows) and B (codes): 128x32 floats each = 1024 float4 each
        #pragma unroll
        for (int q0 = 0; q0 < 4; ++q0) {
            int q = tid + 256 * q0;
            int row = q >> 3, c4 = q & 7;
            const float4 va = *(const float4*)(z   + (size_t)(rbase + row) * D_DIM + dc * TK + c4 * 4);
            *(float4*)(&As[row * LDSS + c4 * 4]) = va;
            const float4 vb = *(const float4*)(cbk + (size_t)(cbase + row) * D_DIM + dc * TK + c4 * 4);
            *(float4*)(&Bs[row * LDSS + c4 * 4]) = vb;
        }
        __syncthreads();
        #pragma unroll
        for (int kq = 0; kq < TK; kq += 4) {
            float4 a[8], b[8];
            #pragma unroll
            for (int i = 0; i < 8; ++i) a[i] = *(const float4*)(&As[(ty + 16 * i) * LDSS + kq]);
            #pragma unroll
            for (int j = 0; j < 8; ++j) b[j] = *(const float4*)(&Bs[(tx + 16 * j) * LDSS + kq]);
            #pragma unroll
            for (int i = 0; i < 8; ++i)
                #pragma unroll
                for (int j = 0; j < 8; ++j) {
                    acc[i][j] += a[i].x * b[j].x;
                    acc[i][j] += a[i].y * b[j].y;
                    acc[i][j] += a[i].z * b[j].z;
                    acc[i][j] += a[i].w * b[j].w;
                }
        }
        __syncthreads();
    }

    // distances + per-thread argmin over its 8 codes, for each of its 8 rows
    float bv[8];
    int   bi[8];
    #pragma unroll
    for (int i = 0; i < 8; ++i) { bv[i] = 3.4e38f; bi[i] = 0; }
    #pragma unroll
    for (int j = 0; j < 8; ++j) {
        int c = cbase + tx + 16 * j;
        float nrm = norms[c];
        #pragma unroll
        for (int i = 0; i < 8; ++i) {
            float dist = nrm - 2.f * acc[i][j];
            if (dist < bv[i] || (dist == bv[i] && c < bi[i])) { bv[i] = dist; bi[i] = c; }
        }
    }

    // cross-thread (tx) reduce via LDS; 16 threads share each row
    // (safe to reuse As/Bs: last loop iteration ended with __syncthreads)
    #pragma unroll
    for (int i = 0; i < 8; ++i) {
        int r = ty + 16 * i;
        As[r * 16 + tx] = bv[i];
        ((int*)Bs)[r * 16 + tx] = bi[i];
    }
    __syncthreads();
    if (tid < TM) {
        int r = tid;
        float v = As[r * 16];
        int idx  = ((int*)Bs)[r * 16];
        #pragma unroll
        for (int t = 1; t < 16; ++t) {
            float v2 = As[r * 16 + t];
            int   i2 = ((int*)Bs)[r * 16 + t];
            if (v2 < v || (v2 == v && i2 < idx)) { v = v2; idx = i2; }
        }
        pval[(size_t)(rbase + r) * 8 + cbl] = v;
        pidx[(size_t)(rbase + r) * 8 + cbl] = idx;
    }
}

// ---------------- merge partials -> final index ----------------
__global__ void merge_kernel(const float* __restrict__ pval, const int* __restrict__ pidx,
                             int* __restrict__ fidx) {
    int row = blockIdx.x * blockDim.x + threadIdx.x;  // grid*block = N
    float v = pval[(size_t)row * 8];
    int idx  = pidx[(size_t)row * 8];
    #pragma unroll
    for (int c = 1; c < 8; ++c) {
        float v2 = pval[(size_t)row * 8 + c];
        int   i2 = pidx[(size_t)row * 8 + c];
        if (v2 < v || (v2 == v && i2 < idx)) { v = v2; idx = i2; }
    }
    fidx[row] = idx;
}

// ---------------- epilogue: copy z_e, gather z_q, loss partial sums ----------------
__global__ void epilogue_kernel(const float* __restrict__ z, const float* __restrict__ cbk,
                                const int* __restrict__ fidx,
                                float* __restrict__ out, float* __restrict__ loss_acc) {
    float lsum = 0.f;
    int stride = gridDim.x * blockDim.x;
    for (int i = blockIdx.x * blockDim.x + threadIdx.x; i < M_ELEMS; i += stride) {
        float ze = z[i];
        int row = i >> 8;       // / D_DIM
        int d   = i & 255;      // % D_DIM
        float zq = cbk[(size_t)fidx[row] * D_DIM + d];
        out[i] = ze;                    // output 0: z_e passthrough
        out[M_ELEMS + 1 + i] = zq;      // output 2: z_q_st == z_q numerically
        float df = zq - ze;
        lsum += df * df;
    }
    #pragma unroll
    for (int off = 32; off; off >>= 1) lsum += __shfl_down(lsum, off);
    if ((threadIdx.x & 63) == 0) atomicAdd(loss_acc, lsum);
}

__global__ void finalize_kernel(const float* __restrict__ loss_acc, float* __restrict__ out) {
    // loss = commitment + codebook = 2 * mean((z_q - z_e)^2)
    out[M_ELEMS] = 2.0f * loss_acc[0] / (float)M_ELEMS;
}

extern "C" void kernel_launch(void* const* d_in, const int* in_sizes, int n_in,
                              void* d_out, int out_size, void* d_ws, size_t ws_size,
                              hipStream_t stream) {
    const float* z   = (const float*)d_in[0];
    const float* cbk = (const float*)d_in[1];
    float* out = (float*)d_out;

    // ws layout (floats): norms[1024] | pval[N*8] | pidx[N*8] (int) | fidx[N] (int) | loss[1]
    float* wsf   = (float*)d_ws;
    float* norms = wsf;
    float* pval  = wsf + K_CODES;
    int*   pidx  = (int*)(pval + (size_t)N_ROWS * 8);
    int*   fidx  = pidx + (size_t)N_ROWS * 8;
    float* loss_acc = (float*)(fidx + N_ROWS);

    hipMemsetAsync(loss_acc, 0, sizeof(float), stream);
    norms_kernel<<<K_CODES / 4, 256, 0, stream>>>(cbk, norms);
    vq_main_kernel<<<(N_ROWS / TM) * (K_CODES / TN), 256, 0, stream>>>(z, cbk, norms, pval, pidx);
    merge_kernel<<<N_ROWS / 256, 256, 0, stream>>>(pval, pidx, fidx);
    epilogue_kernel<<<4096, 256, 0, stream>>>(z, cbk, fidx, out, loss_acc);
    finalize_kernel<<<1, 1, 0, stream>>>(loss_acc, out);
}

// Round 2
// 323.926 us; speedup vs baseline: 1.6356x; 1.6356x over previous
//
#include <hip/hip_runtime.h>

// VQ-VAE quantization, round 2: split-bf16 3-term MFMA distances + exact fp32
// re-check for near-tie rows; atomic-free loss reduction.
// N=32768 rows (D=256), K=1024 codes.
// dist = ||e_k||^2 - 2 z.e_k   (||z||^2 dropped: argmin-invariant)

#define N_ROWS 32768
#define K_CODES 1024
#define D_DIM 256
#define M_ELEMS 8388608   // N_ROWS * D_DIM

#define TM 128
#define TN 128
#define BK 32
#define TAU 0.05f
#define CAP 4096

typedef __attribute__((ext_vector_type(8))) short short8;
typedef __attribute__((ext_vector_type(4))) float f32x4;

__device__ inline unsigned short bf16_rn(float x) {
    unsigned u = __float_as_uint(x);
    unsigned r = u + 0x7FFFu + ((u >> 16) & 1u);
    return (unsigned short)(r >> 16);
}
__device__ inline float bf16_val(unsigned short h) {
    return __uint_as_float(((unsigned)h) << 16);
}

// ---------------- codebook norms (exact fp32) ----------------
__global__ void norms_kernel(const float* __restrict__ cbk, float* __restrict__ norms) {
    int wave = threadIdx.x >> 6;
    int lane = threadIdx.x & 63;
    int code = blockIdx.x * 4 + wave;       // grid = K/4 = 256
    const float4 v = *(const float4*)(cbk + (size_t)code * D_DIM + lane * 4);
    float s = v.x * v.x + v.y * v.y + v.z * v.z + v.w * v.w;
    #pragma unroll
    for (int off = 32; off; off >>= 1) s += __shfl_down(s, off);
    if (lane == 0) norms[code] = s;
}

// ---------------- main: split-bf16 MFMA distances + per-row top-2 ----------------
__global__ __launch_bounds__(256, 2) void vq_main_mfma(
    const float* __restrict__ z, const float* __restrict__ cbk,
    const float* __restrict__ norms,
    float* __restrict__ pval, int* __restrict__ pidx, float* __restrict__ pval2)
{
    __shared__ __align__(16) unsigned short Ah[TM * BK];
    __shared__ __align__(16) unsigned short Al[TM * BK];
    __shared__ __align__(16) unsigned short Bh[TN * BK];
    __shared__ __align__(16) unsigned short Bl[TN * BK];

    const int tid  = threadIdx.x;
    const int bid  = blockIdx.x;            // grid = 256 * 8 = 2048
    const int cbl  = bid & 7;
    const int rb   = bid >> 3;
    const int rbase = rb * TM;
    const int cbase = cbl * TN;

    const int w    = tid >> 6;              // wave 0..3
    const int lane = tid & 63;
    const int quad = lane >> 4;
    const int ml   = lane & 15;
    const int wrow = (w >> 1) * 64;
    const int wcol = (w & 1) * 64;

    f32x4 acc[4][4];
    #pragma unroll
    for (int i = 0; i < 4; ++i)
        #pragma unroll
        for (int j = 0; j < 4; ++j)
            acc[i][j] = (f32x4){0.f, 0.f, 0.f, 0.f};

    for (int dc = 0; dc < D_DIM / BK; ++dc) {
        // stage + convert: 128x32 floats each for A(z rows) and B(codebook rows)
        #pragma unroll
        for (int q = 0; q < 4; ++q) {
            int idx = tid + 256 * q;        // 0..1023
            int row = idx >> 3;
            int c4  = idx & 7;
            {
                const float4 v = *(const float4*)(z + (size_t)(rbase + row) * D_DIM + dc * BK + c4 * 4);
                ushort4 h, l;
                h.x = bf16_rn(v.x); l.x = bf16_rn(v.x - bf16_val(h.x));
                h.y = bf16_rn(v.y); l.y = bf16_rn(v.y - bf16_val(h.y));
                h.z = bf16_rn(v.z); l.z = bf16_rn(v.z - bf16_val(h.z));
                h.w = bf16_rn(v.w); l.w = bf16_rn(v.w - bf16_val(h.w));
                *(ushort4*)&Ah[row * BK + c4 * 4] = h;
                *(ushort4*)&Al[row * BK + c4 * 4] = l;
            }
            {
                const float4 v = *(const float4*)(cbk + (size_t)(cbase + row) * D_DIM + dc * BK + c4 * 4);
                ushort4 h, l;
                h.x = bf16_rn(v.x); l.x = bf16_rn(v.x - bf16_val(h.x));
                h.y = bf16_rn(v.y); l.y = bf16_rn(v.y - bf16_val(h.y));
                h.z = bf16_rn(v.z); l.z = bf16_rn(v.z - bf16_val(h.z));
                h.w = bf16_rn(v.w); l.w = bf16_rn(v.w - bf16_val(h.w));
                *(ushort4*)&Bh[row * BK + c4 * 4] = h;
                *(ushort4*)&Bl[row * BK + c4 * 4] = l;
            }
        }
        __syncthreads();

        short8 ah[4], al[4];
        #pragma unroll
        for (int i = 0; i < 4; ++i) {
            int r = wrow + i * 16 + ml;
            ah[i] = *(const short8*)&Ah[r * BK + quad * 8];
            al[i] = *(const short8*)&Al[r * BK + quad * 8];
        }
        #pragma unroll
        for (int j = 0; j < 4; ++j) {
            int c = wcol + j * 16 + ml;
            short8 bh = *(const short8*)&Bh[c * BK + quad * 8];
            short8 bl = *(const short8*)&Bl[c * BK + quad * 8];
            #pragma unroll
            for (int i = 0; i < 4; ++i)
                acc[i][j] = __builtin_amdgcn_mfma_f32_16x16x32_bf16(ah[i], bh, acc[i][j], 0, 0, 0);
            #pragma unroll
            for (int i = 0; i < 4; ++i)
                acc[i][j] = __builtin_amdgcn_mfma_f32_16x16x32_bf16(ah[i], bl, acc[i][j], 0, 0, 0);
            #pragma unroll
            for (int i = 0; i < 4; ++i)
                acc[i][j] = __builtin_amdgcn_mfma_f32_16x16x32_bf16(al[i], bh, acc[i][j], 0, 0, 0);
        }
        __syncthreads();
    }

    // ------- per-row top-2 over this block's 128 codes -------
    float nrm[4];
    int   codej[4];
    #pragma unroll
    for (int j = 0; j < 4; ++j) {
        codej[j] = cbase + wcol + j * 16 + ml;
        nrm[j]   = norms[codej[j]];
    }

    // overlay reduction arrays on staging LDS (safe: loop ended with syncthreads)
    float* rv1 = (float*)Ah;   // [128][2]
    int*   rid = (int*)Al;     // [128][2]
    float* rv2 = (float*)Bh;   // [128][2]

    #pragma unroll
    for (int i = 0; i < 4; ++i) {
        #pragma unroll
        for (int r = 0; r < 4; ++r) {
            float m1 = 3.4e38f, m2 = 3.4e38f;
            int   i1 = 0x7FFFFFFF;
            #pragma unroll
            for (int j = 0; j < 4; ++j) {
                float dist = nrm[j] - 2.f * acc[i][j][r];
                int code = codej[j];
                if (dist < m1 || (dist == m1 && code < i1)) { m2 = m1; m1 = dist; i1 = code; }
                else m2 = fminf(m2, dist);
            }
            // reduce across the 16 lanes of this quad (they share the row)
            #pragma unroll
            for (int off = 1; off < 16; off <<= 1) {
                float om1 = __shfl_xor(m1, off);
                int   oi1 = __shfl_xor(i1, off);
                float om2 = __shfl_xor(m2, off);
                if (om1 < m1 || (om1 == m1 && oi1 < i1)) { m2 = fminf(m1, om2); m1 = om1; i1 = oi1; }
                else m2 = fminf(m2, om1);
            }
            if (ml == 0) {
                int rl = wrow + i * 16 + quad * 4 + r;
                rv1[rl * 2 + (w & 1)] = m1;
                rid[rl * 2 + (w & 1)] = i1;
                rv2[rl * 2 + (w & 1)] = m2;
            }
        }
    }
    __syncthreads();

    if (tid < TM) {
        float a1 = rv1[tid * 2 + 0], b1 = rv1[tid * 2 + 1];
        int   ai = rid[tid * 2 + 0], bi = rid[tid * 2 + 1];
        float a2 = rv2[tid * 2 + 0], b2 = rv2[tid * 2 + 1];
        float m1, m2; int i1;
        if (b1 < a1 || (b1 == a1 && bi < ai)) { m1 = b1; i1 = bi; m2 = fminf(a1, b2); }
        else                                  { m1 = a1; i1 = ai; m2 = fminf(a2, b1); }
        size_t o = (size_t)(rbase + tid) * 8 + cbl;
        pval[o] = m1; pidx[o] = i1; pval2[o] = m2;
    }
}

// ---------------- merge 8 partials -> final idx; flag near-ties ----------------
__global__ void merge_kernel(const float* __restrict__ pval, const int* __restrict__ pidx,
                             const float* __restrict__ pval2,
                             int* __restrict__ fidx, int* __restrict__ counter,
                             int* __restrict__ list) {
    int row = blockIdx.x * blockDim.x + threadIdx.x;
    size_t o = (size_t)row * 8;
    float m1 = pval[o]; int i1 = pidx[o]; float m2 = pval2[o];
    #pragma unroll
    for (int c = 1; c < 8; ++c) {
        float b1 = pval[o + c]; int bi = pidx[o + c]; float b2 = pval2[o + c];
        if (b1 < m1 || (b1 == m1 && bi < i1)) { m2 = fminf(m1, b2); m1 = b1; i1 = bi; }
        else m2 = fminf(m2, b1);
    }
    fidx[row] = i1;
    if (m2 - m1 < TAU) {
        int s = atomicAdd(counter, 1);
        if (s < CAP) list[s] = row;
    }
}

// ---------------- exact fp32 re-check for flagged rows ----------------
__global__ void cleanup_kernel(const float* __restrict__ z, const float* __restrict__ cbk,
                               const float* __restrict__ norms,
                               const int* __restrict__ counter, const int* __restrict__ list,
                               int* __restrict__ fidx) {
    __shared__ float sv[256];
    __shared__ int   si[256];
    int count = *counter; if (count > CAP) count = CAP;
    int tid = threadIdx.x;
    for (int f = blockIdx.x; f < count; f += gridDim.x) {
        int row = list[f];
        const float4* zz = (const float4*)(z + (size_t)row * D_DIM);
        float best = 3.4e38f; int bidx = 0x7FFFFFFF;
        #pragma unroll
        for (int c = 0; c < 4; ++c) {
            int code = tid + 256 * c;
            const float4* e = (const float4*)(cbk + (size_t)code * D_DIM);
            float dot = 0.f;
            for (int d = 0; d < D_DIM / 4; ++d) {
                float4 a = zz[d], b = e[d];
                dot += a.x * b.x + a.y * b.y + a.z * b.z + a.w * b.w;
            }
            float dist = norms[code] - 2.f * dot;
            if (dist < best || (dist == best && code < bidx)) { best = dist; bidx = code; }
        }
        sv[tid] = best; si[tid] = bidx;
        __syncthreads();
        for (int s = 128; s; s >>= 1) {
            if (tid < s) {
                if (sv[tid + s] < sv[tid] || (sv[tid + s] == sv[tid] && si[tid + s] < si[tid])) {
                    sv[tid] = sv[tid + s]; si[tid] = si[tid + s];
                }
            }
            __syncthreads();
        }
        if (tid == 0) fidx[row] = si[0];
        __syncthreads();
    }
}

// ---------------- epilogue: copy z_e, gather z_q, atomic-free loss ----------------
__global__ void epilogue_kernel(const float* __restrict__ z, const float* __restrict__ cbk,
                                const int* __restrict__ fidx,
                                float* __restrict__ out, float* __restrict__ partials) {
    __shared__ float wsum[4];
    float lsum = 0.f;
    const int n4 = M_ELEMS / 4;
    int stride = gridDim.x * blockDim.x;
    for (int i4 = blockIdx.x * blockDim.x + threadIdx.x; i4 < n4; i4 += stride) {
        float4 ze = *(const float4*)(z + (size_t)i4 * 4);
        int row = i4 >> 6;               // (i4*4)/256
        int d   = (i4 & 63) * 4;
        float4 zq = *(const float4*)(cbk + (size_t)fidx[row] * D_DIM + d);
        *(float4*)(out + (size_t)i4 * 4) = ze;            // output 0: z_e
        float* o2 = out + M_ELEMS + 1 + (size_t)i4 * 4;   // output 2: z_q_st (misaligned +1)
        o2[0] = zq.x; o2[1] = zq.y; o2[2] = zq.z; o2[3] = zq.w;
        float dx = zq.x - ze.x, dy = zq.y - ze.y, dz = zq.z - ze.z, dw = zq.w - ze.w;
        lsum += dx * dx + dy * dy + dz * dz + dw * dw;
    }
    #pragma unroll
    for (int off = 32; off; off >>= 1) lsum += __shfl_down(lsum, off);
    if ((threadIdx.x & 63) == 0) wsum[threadIdx.x >> 6] = lsum;
    __syncthreads();
    if (threadIdx.x == 0)
        partials[blockIdx.x] = wsum[0] + wsum[1] + wsum[2] + wsum[3];
}

__global__ void finalize_kernel(const float* __restrict__ partials, float* __restrict__ out) {
    __shared__ float wsum[4];
    float s = 0.f;
    for (int i = threadIdx.x; i < 2048; i += 256) s += partials[i];
    #pragma unroll
    for (int off = 32; off; off >>= 1) s += __shfl_down(s, off);
    if ((threadIdx.x & 63) == 0) wsum[threadIdx.x >> 6] = s;
    __syncthreads();
    if (threadIdx.x == 0)
        out[M_ELEMS] = 2.0f * (wsum[0] + wsum[1] + wsum[2] + wsum[3]) / (float)M_ELEMS;
}

extern "C" void kernel_launch(void* const* d_in, const int* in_sizes, int n_in,
                              void* d_out, int out_size, void* d_ws, size_t ws_size,
                              hipStream_t stream) {
    const float* z   = (const float*)d_in[0];
    const float* cbk = (const float*)d_in[1];
    float* out = (float*)d_out;

    // ws layout: norms[1024] | pval[N*8] | pval2[N*8] | pidx[N*8] | fidx[N] |
    //            counter[1] | list[CAP] | partials[2048]
    float* wsf   = (float*)d_ws;
    float* norms = wsf;
    float* pval  = norms + K_CODES;
    float* pval2 = pval + (size_t)N_ROWS * 8;
    int*   pidx  = (int*)(pval2 + (size_t)N_ROWS * 8);
    int*   fidx  = pidx + (size_t)N_ROWS * 8;
    int*   counter = fidx + N_ROWS;
    int*   list  = counter + 1;
    float* partials = (float*)(list + CAP);

    hipMemsetAsync(counter, 0, sizeof(int), stream);
    norms_kernel<<<K_CODES / 4, 256, 0, stream>>>(cbk, norms);
    vq_main_mfma<<<(N_ROWS / TM) * (K_CODES / TN), 256, 0, stream>>>(z, cbk, norms, pval, pidx, pval2);
    merge_kernel<<<N_ROWS / 256, 256, 0, stream>>>(pval, pidx, pval2, fidx, counter, list);
    cleanup_kernel<<<64, 256, 0, stream>>>(z, cbk, norms, counter, list, fidx);
    epilogue_kernel<<<2048, 256, 0, stream>>>(z, cbk, fidx, out, partials);
    finalize_kernel<<<1, 256, 0, stream>>>(partials, out);
}

// Round 3
// 295.811 us; speedup vs baseline: 1.7911x; 1.0950x over previous
//
#include <hip/hip_runtime.h>

// VQ-VAE quantization, round 3: pre-converted split-bf16 (hi/lo) + m97-style
// global_load_lds MFMA main loop + aligned-store epilogue.
// N=32768 rows (D=256), K=1024 codes.
// dist = ||e_k||^2 - 2 z.e_k   (||z||^2 dropped: argmin-invariant)
// z.e computed as hi_a.hi_b + hi_a.lo_b + lo_a.hi_b (3-term split-bf16, err ~4e-5)
// with top-2 gap guard (TAU) + exact fp32 re-check of flagged rows.

#define N_ROWS 32768
#define K_CODES 1024
#define D_DIM 256
#define M_ELEMS 8388608   // N_ROWS * D_DIM

#define TM 128
#define TN 128
#define BK 32
#define TAU 0.05f
#define CAP 8192

typedef __attribute__((ext_vector_type(8))) short short8;
typedef __attribute__((ext_vector_type(4))) float f32x4;
typedef __attribute__((ext_vector_type(4), aligned(4))) float f4u;   // 4B-aligned float4 load

__device__ inline unsigned short bf16_rn(float x) {
    unsigned u = __float_as_uint(x);
    unsigned r = u + 0x7FFFu + ((u >> 16) & 1u);
    return (unsigned short)(r >> 16);
}
__device__ inline float bf16_val(unsigned short h) {
    return __uint_as_float(((unsigned)h) << 16);
}
__device__ inline void async16(const void* g, void* l) {
    __builtin_amdgcn_global_load_lds(
        (const __attribute__((address_space(1))) unsigned int*)g,
        (__attribute__((address_space(3))) unsigned int*)l, 16, 0, 0);
}

// ---------------- pre-convert: fp32 -> bf16 hi + bf16 lo ----------------
__global__ void convert_kernel(const float* __restrict__ src,
                               unsigned short* __restrict__ hi,
                               unsigned short* __restrict__ lo, int n4) {
    int stride = gridDim.x * blockDim.x;
    for (int i = blockIdx.x * blockDim.x + threadIdx.x; i < n4; i += stride) {
        float4 v = *(const float4*)(src + (size_t)i * 4);
        ushort4 h, l;
        h.x = bf16_rn(v.x); l.x = bf16_rn(v.x - bf16_val(h.x));
        h.y = bf16_rn(v.y); l.y = bf16_rn(v.y - bf16_val(h.y));
        h.z = bf16_rn(v.z); l.z = bf16_rn(v.z - bf16_val(h.z));
        h.w = bf16_rn(v.w); l.w = bf16_rn(v.w - bf16_val(h.w));
        *(ushort4*)(hi + (size_t)i * 4) = h;
        *(ushort4*)(lo + (size_t)i * 4) = l;
    }
}

// ---------------- codebook norms (exact fp32) ----------------
__global__ void norms_kernel(const float* __restrict__ cbk, float* __restrict__ norms) {
    int wave = threadIdx.x >> 6;
    int lane = threadIdx.x & 63;
    int code = blockIdx.x * 4 + wave;       // grid = K/4 = 256
    const float4 v = *(const float4*)(cbk + (size_t)code * D_DIM + lane * 4);
    float s = v.x * v.x + v.y * v.y + v.z * v.z + v.w * v.w;
    #pragma unroll
    for (int off = 32; off; off >>= 1) s += __shfl_down(s, off);
    if (lane == 0) norms[code] = s;
}

// ---------------- main: pre-converted bf16, global_load_lds staging ----------------
__global__ __launch_bounds__(256, 2) void vq_main_pre(
    const unsigned short* __restrict__ zhi, const unsigned short* __restrict__ zlo,
    const unsigned short* __restrict__ ehi, const unsigned short* __restrict__ elo,
    const float* __restrict__ norms,
    float* __restrict__ pval, int* __restrict__ pidx, float* __restrict__ pval2)
{
    __shared__ __align__(16) unsigned short Ah[TM * BK];
    __shared__ __align__(16) unsigned short Al[TM * BK];
    __shared__ __align__(16) unsigned short Bh[TN * BK];
    __shared__ __align__(16) unsigned short Bl[TN * BK];

    const int tid  = threadIdx.x;
    const int bid  = blockIdx.x;            // grid = 256 * 8 = 2048
    const int cbl  = bid & 7;
    const int rb   = bid >> 3;
    const int rbase = rb * TM;
    const int cbase = cbl * TN;

    const int w    = tid >> 6;
    const int lane = tid & 63;
    const int quad = lane >> 4;
    const int ml   = lane & 15;
    const int wrow = (w >> 1) * 64;
    const int wcol = (w & 1) * 64;

    f32x4 acc[4][4];
    #pragma unroll
    for (int i = 0; i < 4; ++i)
        #pragma unroll
        for (int j = 0; j < 4; ++j)
            acc[i][j] = (f32x4){0.f, 0.f, 0.f, 0.f};

    for (int dc = 0; dc < D_DIM / BK; ++dc) {
        #pragma unroll
        for (int q = 0; q < 2; ++q) {
            int cc  = q * 256 + tid;        // 0..511 chunks of 16B
            int row = cc >> 2;
            int sg  = cc & 3;
            size_t ga = (size_t)(rbase + row) * D_DIM + dc * BK + sg * 8;
            size_t gb = (size_t)(cbase + row) * D_DIM + dc * BK + sg * 8;
            async16(zhi + ga, &Ah[cc * 8]);
            async16(zlo + ga, &Al[cc * 8]);
            async16(ehi + gb, &Bh[cc * 8]);
            async16(elo + gb, &Bl[cc * 8]);
        }
        __syncthreads();

        short8 ah[4], al[4];
        #pragma unroll
        for (int i = 0; i < 4; ++i) {
            int r = wrow + i * 16 + ml;
            ah[i] = *(const short8*)&Ah[r * BK + quad * 8];
            al[i] = *(const short8*)&Al[r * BK + quad * 8];
        }
        #pragma unroll
        for (int j = 0; j < 4; ++j) {
            int c = wcol + j * 16 + ml;
            short8 bh = *(const short8*)&Bh[c * BK + quad * 8];
            short8 bl = *(const short8*)&Bl[c * BK + quad * 8];
            #pragma unroll
            for (int i = 0; i < 4; ++i)
                acc[i][j] = __builtin_amdgcn_mfma_f32_16x16x32_bf16(ah[i], bh, acc[i][j], 0, 0, 0);
            #pragma unroll
            for (int i = 0; i < 4; ++i)
                acc[i][j] = __builtin_amdgcn_mfma_f32_16x16x32_bf16(ah[i], bl, acc[i][j], 0, 0, 0);
            #pragma unroll
            for (int i = 0; i < 4; ++i)
                acc[i][j] = __builtin_amdgcn_mfma_f32_16x16x32_bf16(al[i], bh, acc[i][j], 0, 0, 0);
        }
        __syncthreads();
    }

    // ------- per-row top-2 over this block's 128 codes -------
    float nrm[4];
    int   codej[4];
    #pragma unroll
    for (int j = 0; j < 4; ++j) {
        codej[j] = cbase + wcol + j * 16 + ml;
        nrm[j]   = norms[codej[j]];
    }

    float* rv1 = (float*)Ah;   // [128][2]
    int*   rid = (int*)Al;
    float* rv2 = (float*)Bh;

    #pragma unroll
    for (int i = 0; i < 4; ++i) {
        #pragma unroll
        for (int r = 0; r < 4; ++r) {
            float m1 = 3.4e38f, m2 = 3.4e38f;
            int   i1 = 0x7FFFFFFF;
            #pragma unroll
            for (int j = 0; j < 4; ++j) {
                float dist = nrm[j] - 2.f * acc[i][j][r];
                int code = codej[j];
                if (dist < m1 || (dist == m1 && code < i1)) { m2 = m1; m1 = dist; i1 = code; }
                else m2 = fminf(m2, dist);
            }
            #pragma unroll
            for (int off = 1; off < 16; off <<= 1) {
                float om1 = __shfl_xor(m1, off);
                int   oi1 = __shfl_xor(i1, off);
                float om2 = __shfl_xor(m2, off);
                if (om1 < m1 || (om1 == m1 && oi1 < i1)) { m2 = fminf(m1, om2); m1 = om1; i1 = oi1; }
                else m2 = fminf(m2, om1);
            }
            if (ml == 0) {
                int rl = wrow + i * 16 + quad * 4 + r;
                rv1[rl * 2 + (w & 1)] = m1;
                rid[rl * 2 + (w & 1)] = i1;
                rv2[rl * 2 + (w & 1)] = m2;
            }
        }
    }
    __syncthreads();

    if (tid < TM) {
        float a1 = rv1[tid * 2 + 0], b1 = rv1[tid * 2 + 1];
        int   ai = rid[tid * 2 + 0], bi = rid[tid * 2 + 1];
        float a2 = rv2[tid * 2 + 0], b2 = rv2[tid * 2 + 1];
        float m1, m2; int i1;
        if (b1 < a1 || (b1 == a1 && bi < ai)) { m1 = b1; i1 = bi; m2 = fminf(a1, b2); }
        else                                  { m1 = a1; i1 = ai; m2 = fminf(a2, b1); }
        size_t o = (size_t)(rbase + tid) * 8 + cbl;
        pval[o] = m1; pidx[o] = i1; pval2[o] = m2;
    }
}

// ---------------- fallback main (round-2 style, convert in-kernel) ----------------
__global__ __launch_bounds__(256, 2) void vq_main_mfma(
    const float* __restrict__ z, const float* __restrict__ cbk,
    const float* __restrict__ norms,
    float* __restrict__ pval, int* __restrict__ pidx, float* __restrict__ pval2)
{
    __shared__ __align__(16) unsigned short Ah[TM * BK];
    __shared__ __align__(16) unsigned short Al[TM * BK];
    __shared__ __align__(16) unsigned short Bh[TN * BK];
    __shared__ __align__(16) unsigned short Bl[TN * BK];

    const int tid  = threadIdx.x;
    const int bid  = blockIdx.x;
    const int cbl  = bid & 7;
    const int rb   = bid >> 3;
    const int rbase = rb * TM;
    const int cbase = cbl * TN;

    const int w    = tid >> 6;
    const int lane = tid & 63;
    const int quad = lane >> 4;
    const int ml   = lane & 15;
    const int wrow = (w >> 1) * 64;
    const int wcol = (w & 1) * 64;

    f32x4 acc[4][4];
    #pragma unroll
    for (int i = 0; i < 4; ++i)
        #pragma unroll
        for (int j = 0; j < 4; ++j)
            acc[i][j] = (f32x4){0.f, 0.f, 0.f, 0.f};

    for (int dc = 0; dc < D_DIM / BK; ++dc) {
        #pragma unroll
        for (int q = 0; q < 4; ++q) {
            int idx = tid + 256 * q;
            int row = idx >> 3;
            int c4  = idx & 7;
            {
                const float4 v = *(const float4*)(z + (size_t)(rbase + row) * D_DIM + dc * BK + c4 * 4);
                ushort4 h, l;
                h.x = bf16_rn(v.x); l.x = bf16_rn(v.x - bf16_val(h.x));
                h.y = bf16_rn(v.y); l.y = bf16_rn(v.y - bf16_val(h.y));
                h.z = bf16_rn(v.z); l.z = bf16_rn(v.z - bf16_val(h.z));
                h.w = bf16_rn(v.w); l.w = bf16_rn(v.w - bf16_val(h.w));
                *(ushort4*)&Ah[row * BK + c4 * 4] = h;
                *(ushort4*)&Al[row * BK + c4 * 4] = l;
            }
            {
                const float4 v = *(const float4*)(cbk + (size_t)(cbase + row) * D_DIM + dc * BK + c4 * 4);
                ushort4 h, l;
                h.x = bf16_rn(v.x); l.x = bf16_rn(v.x - bf16_val(h.x));
                h.y = bf16_rn(v.y); l.y = bf16_rn(v.y - bf16_val(h.y));
                h.z = bf16_rn(v.z); l.z = bf16_rn(v.z - bf16_val(h.z));
                h.w = bf16_rn(v.w); l.w = bf16_rn(v.w - bf16_val(h.w));
                *(ushort4*)&Bh[row * BK + c4 * 4] = h;
                *(ushort4*)&Bl[row * BK + c4 * 4] = l;
            }
        }
        __syncthreads();

        short8 ah[4], al[4];
        #pragma unroll
        for (int i = 0; i < 4; ++i) {
            int r = wrow + i * 16 + ml;
            ah[i] = *(const short8*)&Ah[r * BK + quad * 8];
            al[i] = *(const short8*)&Al[r * BK + quad * 8];
        }
        #pragma unroll
        for (int j = 0; j < 4; ++j) {
            int c = wcol + j * 16 + ml;
            short8 bh = *(const short8*)&Bh[c * BK + quad * 8];
            short8 bl = *(const short8*)&Bl[c * BK + quad * 8];
            #pragma unroll
            for (int i = 0; i < 4; ++i)
                acc[i][j] = __builtin_amdgcn_mfma_f32_16x16x32_bf16(ah[i], bh, acc[i][j], 0, 0, 0);
            #pragma unroll
            for (int i = 0; i < 4; ++i)
                acc[i][j] = __builtin_amdgcn_mfma_f32_16x16x32_bf16(ah[i], bl, acc[i][j], 0, 0, 0);
            #pragma unroll
            for (int i = 0; i < 4; ++i)
                acc[i][j] = __builtin_amdgcn_mfma_f32_16x16x32_bf16(al[i], bh, acc[i][j], 0, 0, 0);
        }
        __syncthreads();
    }

    float nrm[4];
    int   codej[4];
    #pragma unroll
    for (int j = 0; j < 4; ++j) {
        codej[j] = cbase + wcol + j * 16 + ml;
        nrm[j]   = norms[codej[j]];
    }
    float* rv1 = (float*)Ah;
    int*   rid = (int*)Al;
    float* rv2 = (float*)Bh;
    #pragma unroll
    for (int i = 0; i < 4; ++i) {
        #pragma unroll
        for (int r = 0; r < 4; ++r) {
            float m1 = 3.4e38f, m2 = 3.4e38f;
            int   i1 = 0x7FFFFFFF;
            #pragma unroll
            for (int j = 0; j < 4; ++j) {
                float dist = nrm[j] - 2.f * acc[i][j][r];
                int code = codej[j];
                if (dist < m1 || (dist == m1 && code < i1)) { m2 = m1; m1 = dist; i1 = code; }
                else m2 = fminf(m2, dist);
            }
            #pragma unroll
            for (int off = 1; off < 16; off <<= 1) {
                float om1 = __shfl_xor(m1, off);
                int   oi1 = __shfl_xor(i1, off);
                float om2 = __shfl_xor(m2, off);
                if (om1 < m1 || (om1 == m1 && oi1 < i1)) { m2 = fminf(m1, om2); m1 = om1; i1 = oi1; }
                else m2 = fminf(m2, om1);
            }
            if (ml == 0) {
                int rl = wrow + i * 16 + quad * 4 + r;
                rv1[rl * 2 + (w & 1)] = m1;
                rid[rl * 2 + (w & 1)] = i1;
                rv2[rl * 2 + (w & 1)] = m2;
            }
        }
    }
    __syncthreads();
    if (tid < TM) {
        float a1 = rv1[tid * 2 + 0], b1 = rv1[tid * 2 + 1];
        int   ai = rid[tid * 2 + 0], bi = rid[tid * 2 + 1];
        float a2 = rv2[tid * 2 + 0], b2 = rv2[tid * 2 + 1];
        float m1, m2; int i1;
        if (b1 < a1 || (b1 == a1 && bi < ai)) { m1 = b1; i1 = bi; m2 = fminf(a1, b2); }
        else                                  { m1 = a1; i1 = ai; m2 = fminf(a2, b1); }
        size_t o = (size_t)(rbase + tid) * 8 + cbl;
        pval[o] = m1; pidx[o] = i1; pval2[o] = m2;
    }
}

// ---------------- merge 8 partials -> final idx; flag near-ties ----------------
__global__ void merge_kernel(const float* __restrict__ pval, const int* __restrict__ pidx,
                             const float* __restrict__ pval2,
                             int* __restrict__ fidx, int* __restrict__ counter,
                             int* __restrict__ list) {
    int row = blockIdx.x * blockDim.x + threadIdx.x;
    size_t o = (size_t)row * 8;
    float m1 = pval[o]; int i1 = pidx[o]; float m2 = pval2[o];
    #pragma unroll
    for (int c = 1; c < 8; ++c) {
        float b1 = pval[o + c]; int bi = pidx[o + c]; float b2 = pval2[o + c];
        if (b1 < m1 || (b1 == m1 && bi < i1)) { m2 = fminf(m1, b2); m1 = b1; i1 = bi; }
        else m2 = fminf(m2, b1);
    }
    fidx[row] = i1;
    if (m2 - m1 < TAU) {
        int s = atomicAdd(counter, 1);
        if (s < CAP) list[s] = row;
    }
}

// ---------------- exact fp32 re-check for flagged rows ----------------
__global__ void cleanup_kernel(const float* __restrict__ z, const float* __restrict__ cbk,
                               const float* __restrict__ norms,
                               const int* __restrict__ counter, const int* __restrict__ list,
                               int* __restrict__ fidx) {
    __shared__ float sv[256];
    __shared__ int   si[256];
    int count = *counter; if (count > CAP) count = CAP;
    int tid = threadIdx.x;
    for (int f = blockIdx.x; f < count; f += gridDim.x) {
        int row = list[f];
        const float4* zz = (const float4*)(z + (size_t)row * D_DIM);
        float best = 3.4e38f; int bidx = 0x7FFFFFFF;
        #pragma unroll
        for (int c = 0; c < 4; ++c) {
            int code = tid + 256 * c;
            const float4* e = (const float4*)(cbk + (size_t)code * D_DIM);
            float dot = 0.f;
            for (int d = 0; d < D_DIM / 4; ++d) {
                float4 a = zz[d], b = e[d];
                dot += a.x * b.x + a.y * b.y + a.z * b.z + a.w * b.w;
            }
            float dist = norms[code] - 2.f * dot;
            if (dist < best || (dist == best && code < bidx)) { best = dist; bidx = code; }
        }
        sv[tid] = best; si[tid] = bidx;
        __syncthreads();
        for (int s = 128; s; s >>= 1) {
            if (tid < s) {
                if (sv[tid + s] < sv[tid] || (sv[tid + s] == sv[tid] && si[tid + s] < si[tid])) {
                    sv[tid] = sv[tid + s]; si[tid] = si[tid + s];
                }
            }
            __syncthreads();
        }
        if (tid == 0) fidx[row] = si[0];
        __syncthreads();
    }
}

// ---------------- epilogue: all-aligned stores ----------------
// phase 1: copy z_e + loss (aligned loads+stores).
// phase 2: z_q region (out+M+1): groups shifted to i===3 (mod 4) so the 16B
//          stores are aligned; misalignment moves to codebook loads (L2-hit).
__global__ void epilogue_kernel(const float* __restrict__ z, const float* __restrict__ cbk,
                                const int* __restrict__ fidx,
                                float* __restrict__ out, float* __restrict__ partials) {
    __shared__ float wsum[4];
    const int gtid = blockIdx.x * blockDim.x + threadIdx.x;
    const int stride = gridDim.x * blockDim.x;
    float lsum = 0.f;

    // phase 1
    const int n4 = M_ELEMS / 4;
    for (int i4 = gtid; i4 < n4; i4 += stride) {
        float4 ze = *(const float4*)(z + (size_t)i4 * 4);
        int row = i4 >> 6;
        int d   = (i4 & 63) * 4;
        float4 zq = *(const float4*)(cbk + (size_t)fidx[row] * D_DIM + d);
        *(float4*)(out + (size_t)i4 * 4) = ze;
        float dx = zq.x - ze.x, dy = zq.y - ze.y, dz = zq.z - ze.z, dw = zq.w - ze.w;
        lsum += dx * dx + dy * dy + dz * dz + dw * dw;
    }

    // phase 2
    float* out2 = out + M_ELEMS + 1;
    const int g2 = (M_ELEMS - 4) / 4;      // groups i0 = 3+4g, covers i=3..M-2
    for (int g = gtid; g < g2; g += stride) {
        int i0 = 3 + 4 * g;
        int row = i0 >> 8;
        int d0  = i0 & 255;
        float4 v;
        if (d0 <= D_DIM - 4) {
            f4u t = *(const f4u*)(cbk + (size_t)fidx[row] * D_DIM + d0);
            v = (float4){t.x, t.y, t.z, t.w};
        } else {
            #pragma unroll
            for (int t = 0; t < 4; ++t) {
                int i = i0 + t;
                ((float*)&v)[t] = cbk[(size_t)fidx[i >> 8] * D_DIM + (i & 255)];
            }
        }
        *(float4*)(out2 + i0) = v;         // addr = out + M + 4 + 4g : 16B aligned
    }
    if (gtid == 0) {
        out2[0] = cbk[(size_t)fidx[0] * D_DIM + 0];
        out2[1] = cbk[(size_t)fidx[0] * D_DIM + 1];
        out2[2] = cbk[(size_t)fidx[0] * D_DIM + 2];
        out2[M_ELEMS - 1] = cbk[(size_t)fidx[N_ROWS - 1] * D_DIM + 255];
    }

    #pragma unroll
    for (int off = 32; off; off >>= 1) lsum += __shfl_down(lsum, off);
    if ((threadIdx.x & 63) == 0) wsum[threadIdx.x >> 6] = lsum;
    __syncthreads();
    if (threadIdx.x == 0)
        partials[blockIdx.x] = wsum[0] + wsum[1] + wsum[2] + wsum[3];
}

__global__ void finalize_kernel(const float* __restrict__ partials, float* __restrict__ out) {
    __shared__ float wsum[4];
    float s = 0.f;
    for (int i = threadIdx.x; i < 2048; i += 256) s += partials[i];
    #pragma unroll
    for (int off = 32; off; off >>= 1) s += __shfl_down(s, off);
    if ((threadIdx.x & 63) == 0) wsum[threadIdx.x >> 6] = s;
    __syncthreads();
    if (threadIdx.x == 0)
        out[M_ELEMS] = 2.0f * (wsum[0] + wsum[1] + wsum[2] + wsum[3]) / (float)M_ELEMS;
}

extern "C" void kernel_launch(void* const* d_in, const int* in_sizes, int n_in,
                              void* d_out, int out_size, void* d_ws, size_t ws_size,
                              hipStream_t stream) {
    const float* z   = (const float*)d_in[0];
    const float* cbk = (const float*)d_in[1];
    float* out = (float*)d_out;

    char* ws = (char*)d_ws;
    // pre-converted path layout (bytes):
    unsigned short* zhi = (unsigned short*)ws;                       // 16 MB
    unsigned short* zlo = zhi + (size_t)M_ELEMS;                     // 16 MB
    unsigned short* ehi = zlo + (size_t)M_ELEMS;                     // 512 KB
    unsigned short* elo = ehi + (size_t)K_CODES * D_DIM;             // 512 KB
    float* norms = (float*)(elo + (size_t)K_CODES * D_DIM);
    float* pval  = norms + K_CODES;
    float* pval2 = pval + (size_t)N_ROWS * 8;
    int*   pidx  = (int*)(pval2 + (size_t)N_ROWS * 8);
    int*   fidx  = pidx + (size_t)N_ROWS * 8;
    int*   counter = fidx + N_ROWS;
    int*   list  = counter + 16;            // pad
    float* partials = (float*)(list + CAP);
    size_t need = (size_t)((char*)(partials + 2048) - ws);

    bool pre = ws_size >= need;
    if (!pre) {
        // fallback layout (small): norms | pval | pval2 | pidx | fidx | counter | list | partials
        norms = (float*)ws;
        pval  = norms + K_CODES;
        pval2 = pval + (size_t)N_ROWS * 8;
        pidx  = (int*)(pval2 + (size_t)N_ROWS * 8);
        fidx  = pidx + (size_t)N_ROWS * 8;
        counter = fidx + N_ROWS;
        list  = counter + 16;
        partials = (float*)(list + CAP);
    }

    hipMemsetAsync(counter, 0, sizeof(int), stream);
    norms_kernel<<<K_CODES / 4, 256, 0, stream>>>(cbk, norms);
    if (pre) {
        convert_kernel<<<1024, 256, 0, stream>>>(z, zhi, zlo, M_ELEMS / 4);
        convert_kernel<<<64, 256, 0, stream>>>(cbk, ehi, elo, K_CODES * D_DIM / 4);
        vq_main_pre<<<(N_ROWS / TM) * (K_CODES / TN), 256, 0, stream>>>(
            zhi, zlo, ehi, elo, norms, pval, pidx, pval2);
    } else {
        vq_main_mfma<<<(N_ROWS / TM) * (K_CODES / TN), 256, 0, stream>>>(
            z, cbk, norms, pval, pidx, pval2);
    }
    merge_kernel<<<N_ROWS / 256, 256, 0, stream>>>(pval, pidx, pval2, fidx, counter, list);
    cleanup_kernel<<<64, 256, 0, stream>>>(z, cbk, norms, counter, list, fidx);
    epilogue_kernel<<<2048, 256, 0, stream>>>(z, cbk, fidx, out, partials);
    finalize_kernel<<<1, 256, 0, stream>>>(partials, out);
}